// Round 8
// baseline (746.325 us; speedup 1.0000x reference)
//
#include <hip/hip_runtime.h>
#include <hip/hip_bf16.h>

// Problem constants (from setup_inputs)
#define N_NODES 20000
#define NANG 8
#define CH 64                      // in_size == out_size == 64
#define M_ROWS (NANG * N_NODES)    // 160000
#define E_EDGES (M_ROWS * 16)      // 2560000
#define K_CHEB 8
#define WK_STRIDE (NANG * CH * CH) // 32768 floats per weight[k]
#define BROWS 256                  // rows per bucket (good scatter write-combining)
#define NB (M_ROWS / BROWS)        // 625 buckets
#define NCHUNK 512                 // r6: counting-sort scatter, 5000-edge chunks
#define CHUNK (E_EDGES / NCHUNK)   // 5000
#define SCAN_K (NCHUNK / 256)      // 2 chunks per thread in bscan2
#define SC_RE 20                   // ceil(CHUNK/256) reg-staged edges per thread
#define RPW 4                      // r8: back to 4 (r7's 8 halved TLP, regressed)
#define SPMM_BLOCKS (M_ROWS / (4 * RPW))  // 10000 blocks x 4 waves
#define KCAT 3648                  // 64 (x@Wsum) + 7*512 (feat(Tk)@Wk)
#define SK_TOTAL 114               // KCAT/32 ksteps
#define BCAP 5120                  // LDS staging cap (mean 4096, sd 64 -> 16 sigma)
#define GROWS 32                   // gemm rows per block (2 row-groups)
#define GEMM_BLOCKS (N_NODES / GROWS)  // 625

typedef short short8 __attribute__((ext_vector_type(8)));
typedef float f32x4 __attribute__((ext_vector_type(4)));

__device__ __forceinline__ float bf2f(ushort u) {
    return __uint_as_float((unsigned int)u << 16);
}

// ---------------- deterministic bucket build (no global atomics) ----------------

__global__ __launch_bounds__(256) void count_kernel(const int* __restrict__ rows,
                                                    int* __restrict__ chunk_cnt) {
    __shared__ int h[NB];
    int c = blockIdx.x, tid = threadIdx.x;
    for (int i = tid; i < NB; i += 256) h[i] = 0;
    __syncthreads();
    int base = c * CHUNK;
    for (int i = tid; i < CHUNK; i += 256) atomicAdd(&h[rows[base + i] >> 8], 1);
    __syncthreads();
    for (int i = tid; i < NB; i += 256) chunk_cnt[(size_t)c * NB + i] = h[i];
}

// per-bucket scan along the chunk axis. 256 threads x SCAN_K serial chunks each,
// Hillis-Steele over the 256 partials, write back exclusive prefixes.
// chunk_cnt[c][b] -> exclusive prefix over c (bucket-local), btotal[b] = total.
__global__ __launch_bounds__(256) void bscan2_kernel(int* __restrict__ chunk_cnt,
                                                     int* __restrict__ btotal) {
    __shared__ int s[256];
    int b = blockIdx.x, t = threadIdx.x;
    int loc[SCAN_K];
    int sum = 0;
#pragma unroll
    for (int k = 0; k < SCAN_K; ++k) {
        loc[k] = chunk_cnt[(size_t)(t * SCAN_K + k) * NB + b];
        sum += loc[k];
    }
    s[t] = sum;
    __syncthreads();
#pragma unroll
    for (int off = 1; off < 256; off <<= 1) {
        int u = (t >= off) ? s[t - off] : 0;
        __syncthreads();
        s[t] += u;
        __syncthreads();
    }
    int run = s[t] - sum;                 // exclusive prefix of this thread's span
#pragma unroll
    for (int k = 0; k < SCAN_K; ++k) {
        chunk_cnt[(size_t)(t * SCAN_K + k) * NB + b] = run;
        run += loc[k];
    }
    if (t == 255) btotal[b] = s[255];
}

// single-block exclusive scan over NB bucket totals (NB=625 <= 1024)
__global__ void bscan_kernel(const int* __restrict__ btotal, int* __restrict__ bstart) {
    __shared__ int s[1024];
    int t = threadIdx.x;
    int v = (t < NB) ? btotal[t] : 0;
    s[t] = v;
    __syncthreads();
    for (int off = 1; off < 1024; off <<= 1) {
        int u = (t >= off) ? s[t - off] : 0;
        __syncthreads();
        s[t] += u;
        __syncthreads();
    }
    if (t < NB) bstart[t] = s[t] - v;
    if (t == 1023) bstart[NB] = s[1023];
}

// ---------------- scatter v2: LDS counting sort -> SEQUENTIAL global writes -----
// r5 evidence: occupancy 11->43% with duration UNCHANGED (63us) -> scatter was
// bound by the random-8B-write transaction path. Bucket-sort each chunk in LDS,
// write out in sorted order: slot i -> gaddr[bkey[i]] + i, contiguous per run.

__global__ __launch_bounds__(256) void scatter_kernel(
        const int* __restrict__ rows, const int* __restrict__ cols,
        const float* __restrict__ vals, const int* __restrict__ chunk_cnt,
        const int* __restrict__ bstart, int2* __restrict__ bedges) {
    __shared__ int2 stage[CHUNK];      // 40 KB, bucket-sorted edges
    __shared__ ushort bkey[CHUNK];     // 10 KB, bucket id per sorted slot
    __shared__ int hist[NB];
    __shared__ int fill[NB];
    __shared__ int gaddr[NB];          // bstart[b] + chunk_cnt[c][b] - lstart[b]
    __shared__ int sc[256];
    int c = blockIdx.x, tid = threadIdx.x;
    for (int i = tid; i < NB; i += 256) hist[i] = 0;
    __syncthreads();

    // phase A: reg-stage this thread's edges, count buckets
    int base = c * CHUNK;
    int2 eds[SC_RE];
    int keys[SC_RE];
#pragma unroll
    for (int k = 0; k < SC_RE; ++k) {
        int i = tid + k * 256;
        if (i < CHUNK) {
            int e = base + i;
            int r = rows[e];
            eds[k] = make_int2(cols[e] | ((r & 255) << 18), __float_as_int(vals[e]));
            keys[k] = r >> 8;
            atomicAdd(&hist[keys[k]], 1);
        } else keys[k] = -1;
    }
    __syncthreads();

    // phase B: exclusive scan of hist (3 slots/thread, 768 >= NB)
    int loc[3];
    int sum = 0;
    int b0 = tid * 3;
#pragma unroll
    for (int k = 0; k < 3; ++k) {
        int b = b0 + k;
        loc[k] = (b < NB) ? hist[b] : 0;
        sum += loc[k];
    }
    sc[tid] = sum;
    __syncthreads();
#pragma unroll
    for (int off = 1; off < 256; off <<= 1) {
        int u = (tid >= off) ? sc[tid - off] : 0;
        __syncthreads();
        sc[tid] += u;
        __syncthreads();
    }
    int run = sc[tid] - sum;
#pragma unroll
    for (int k = 0; k < 3; ++k) {
        int b = b0 + k;
        if (b < NB) {
            fill[b] = run;
            gaddr[b] = bstart[b] + chunk_cnt[(size_t)c * NB + b] - run;
        }
        run += loc[k];
    }
    __syncthreads();

    // phase C: scatter regs -> bucket-sorted LDS
#pragma unroll
    for (int k = 0; k < SC_RE; ++k) {
        if (keys[k] >= 0) {
            int p = atomicAdd(&fill[keys[k]], 1);
            stage[p] = eds[k];
            bkey[p] = (ushort)keys[k];
        }
    }
    __syncthreads();

    // phase D: sequential write-out (runs contiguous in global too)
    for (int i = tid; i < CHUNK; i += 256) {
        int b = bkey[i];
        bedges[gaddr[b] + i] = stage[i];
    }
}

// per-bucket: group edges by row via LDS staging, then write bout SEQUENTIALLY
// (coalesced; avoids random-8B write amplification). Parallel scan for prefix.
__global__ __launch_bounds__(256) void bucket_group_kernel(
        const int* __restrict__ bstart, const int2* __restrict__ bin,
        int2* __restrict__ bout, int* __restrict__ row_start) {
    __shared__ int cnt[BROWS];
    __shared__ int pref[BROWS];
    __shared__ int fill[BROWS];
    __shared__ int2 ob[BCAP];          // 40 KB staging
    int b = blockIdx.x, tid = threadIdx.x;
    int s = bstart[b], e = bstart[b + 1];
    int n = e - s;
    cnt[tid] = 0;
    __syncthreads();
    int2 eds[20];                      // reg cache (n/256 <= 20 when n <= BCAP)
    int ni = 0;
    for (int i = tid; i < n; i += 256, ++ni) {
        int2 ed = bin[s + i];
        if (ni < 20) eds[ni] = ed;
        atomicAdd(&cnt[(ed.x >> 18) & 255], 1);
    }
    __syncthreads();
    // Hillis-Steele inclusive scan over 256 counters -> exclusive pref
    int v = cnt[tid];
    pref[tid] = v;
    __syncthreads();
#pragma unroll
    for (int off = 1; off < 256; off <<= 1) {
        int u = (tid >= off) ? pref[tid - off] : 0;
        __syncthreads();
        pref[tid] += u;
        __syncthreads();
    }
    int my_excl = pref[tid] - v;
    __syncthreads();
    pref[tid] = my_excl;
    fill[tid] = my_excl;
    __syncthreads();

    if (n <= BCAP) {
        ni = 0;
        for (int i = tid; i < n; i += 256, ++ni) {
            int2 ed = (ni < 20) ? eds[ni] : bin[s + i];
            int p = atomicAdd(&fill[(ed.x >> 18) & 255], 1);
            ob[p] = make_int2(ed.x & 0x3ffff, ed.y);
        }
        __syncthreads();
        for (int i = tid; i < n; i += 256)
            bout[s + i] = ob[i];       // sequential, coalesced
    } else {
        // fallback (statistically unreachable): direct global scatter
        ni = 0;
        for (int i = tid; i < n; i += 256, ++ni) {
            int2 ed = (ni < 20) ? eds[ni] : bin[s + i];
            int p = atomicAdd(&fill[(ed.x >> 18) & 255], 1);
            bout[s + p] = make_int2(ed.x & 0x3ffff, ed.y);
        }
    }
    row_start[b * BROWS + tid] = s + pref[tid];
    if (b == NB - 1 && tid == 0) row_start[M_ROWS] = e;
}

// ---------------- small converts ----------------

__global__ void xconv_kernel(const float* __restrict__ x, ushort* __restrict__ xb) {
    int i = blockIdx.x * 256 + threadIdx.x;
    __hip_bfloat16 v = __float2bfloat16(x[i]);
    xb[i] = *(ushort*)&v;
}

// Wcat[n][kkc], kkc in [0,KCAT): kkc<64 -> sum_a W[0][a*64+kkc][n] (x@Wsum term);
// else k=(kkc-64)/512+1, kk=(kkc-64)%512 -> W[k][kk][n].
__global__ void wcat_kernel(const float* __restrict__ W, ushort* __restrict__ Wcat) {
    int idx = blockIdx.x * 256 + threadIdx.x;    // 64*KCAT = 233472
    int n   = idx / KCAT;
    int kkc = idx - n * KCAT;
    float v;
    if (kkc < 64) {
        v = 0.f;
#pragma unroll
        for (int a = 0; a < NANG; ++a) v += W[(a * 64 + kkc) * 64 + n];
    } else {
        int k  = ((kkc - 64) >> 9) + 1;
        int kk = (kkc - 64) & 511;
        v = W[(size_t)k * WK_STRIDE + kk * 64 + n];
    }
    __hip_bfloat16 b = __float2bfloat16(v);
    Wcat[idx] = *(ushort*)&b;
}

// ---------------- SpMM v5: SCALAR edge loads (no readlanes) ----------------
// r7 lesson: occupancy knobs are exhausted (3x flat). Remaining VALU cost per
// edge was 2 v_readlane + lshl + fmac (~8cy); the edge block address is
// WAVE-UNIFORM, so load it through the SCALAR pipe instead: edges[base+i] with
// uniform base + literal i -> s_load_dwordx2 (merged to x8/x16); cols/weights
// land in SGPRs directly. Deletes all readlanes + the vector edge load:
// VALU/edge = lshl + fmac = 2; edge traffic moves to the independent scalar
// cache (lgkmcnt), vector pipe carries only the 16-outstanding gathers.
// Tail edges past e read the NEXT row's edges (valid; weight s_cselect'ed to 0);
// the final <=15 slots of the whole array read past E_EDGES into the adjacent
// workspace region -- s_min clamp on col keeps the gather address in-bounds.

template <int TIN_TILED, int TSUB_MODE>
__global__ __launch_bounds__(256) void spmm_kernel(
        const int* __restrict__ row_start, const int2* __restrict__ edges,
        const ushort* __restrict__ Tin, const ushort* __restrict__ Tsub,
        ushort* __restrict__ Tout, float alpha, float beta) {
    int wid = (blockIdx.x * 256 + threadIdx.x) >> 6;
    int lane = threadIdx.x & 63;
    int r0 = wid * RPW;                // M_ROWS % (4*RPW) == 0 -> always in range

    // scalar row bounds for RPW rows (uniform addresses -> s_load, issued together)
    int sb[RPW + 1];
#pragma unroll
    for (int j = 0; j <= RPW; ++j)
        sb[j] = __builtin_amdgcn_readfirstlane(row_start[r0 + j]);

#pragma unroll
    for (int j = 0; j < RPW; ++j) {
        int s = sb[j], e = sb[j + 1];
        float acc0 = 0.f, acc1 = 0.f;
        for (int base = s; base < e; base += 16) {
            // 16 edges via scalar loads (uniform base) -> SGPRs
            int col[16], wb[16];
#pragma unroll
            for (int i = 0; i < 16; ++i) {
                int2 ed = edges[base + i];           // s_load (uniform addr)
                col[i] = __builtin_amdgcn_readfirstlane(ed.x);
                wb[i]  = __builtin_amdgcn_readfirstlane(ed.y);
            }
            // batch the 16 gathers: pure-load loop -> 16 outstanding (1 round-trip)
            ushort raw[16];
#pragma unroll
            for (int i = 0; i < 16; ++i) {
                unsigned c = min((unsigned)col[i], (unsigned)(M_ROWS - 1)); // s_min
                if (TIN_TILED) c %= N_NODES;         // scalar magic-div
                raw[i] = Tin[(size_t)c * CH + lane]; // saddr + lane offset
            }
#pragma unroll
            for (int i = 0; i < 16; ++i) {
                int w = (base + i < e) ? wb[i] : 0;  // s_cselect (0.0f bits)
                float t = bf2f(raw[i]);
                if (i & 1) acc1 = fmaf(__int_as_float(w), t, acc1);
                else       acc0 = fmaf(__int_as_float(w), t, acc0);
            }
        }
        int r = r0 + j;
        float v = alpha * (acc0 + acc1);
        size_t oi = (size_t)r * CH + lane;
        if (TSUB_MODE == 1) v += beta * bf2f(Tsub[oi]);
        if (TSUB_MODE == 2) v += beta * bf2f(Tsub[(size_t)((unsigned)r % N_NODES) * CH + lane]);
        __hip_bfloat16 o = __float2bfloat16(v);
        Tout[oi] = *(ushort*)&o;
    }
}

// ---------------- concatenated GEMM, K-split + register M-blocking (r6 form) ------
// r7 evidence: 8-wave split (2x waves, occ 21->41%) did NOT help (62.2->64.9us)
// -> gemm is not wave-starved; reverted to the best-measured r6 config:
// 625 blocks x 256 thr (4 waves), 32 rows/block, wave w ksteps [2+28w,2+28w+28),
// each B-fragment feeds 2 MFMAs, LDS 16 KB, single residency generation.
// A layout: m=lane&15, k=(lane>>4)*8+j. C/D: col=lane&15, row=(lane>>4)*4+reg [m89].

__global__ __launch_bounds__(256) void gemm_cat_kernel(
        const ushort* __restrict__ xb,    // [N,64]
        const ushort* __restrict__ Tall,  // [7][NANG*N,64]
        const ushort* __restrict__ Wcat,  // [64][KCAT]
        const float* __restrict__ bias,
        float* __restrict__ out) {        // [N,64] fp32
    __shared__ float red[4][16][64];      // 16 KB, conflict-free, reused per rg
    int m0 = blockIdx.x * GROWS;
    int w = threadIdx.x >> 6;             // K-split index 0..3
    int l = threadIdx.x & 63;
    int lm = l & 15;
    int lq = l >> 4;
    const short* Xp = (const short*)xb;
    const short* Tp = (const short*)Tall;
    const short* Wp = (const short*)Wcat;

    f32x4 acc[2][4];
#pragma unroll
    for (int rg = 0; rg < 2; ++rg)
#pragma unroll
        for (int t = 0; t < 4; ++t) acc[rg][t] = (f32x4){0.f, 0.f, 0.f, 0.f};

    // A-fragment load for a T-kstep (sk in [2,114)): seg=(sk-2)>>4, ks=(sk-2)&15,
    // a=ks>>1, half=ks&1.
    auto LDA = [&](int sk, int rg) -> short8 {
        int u = sk - 2;
        return *(const short8*)(Tp
            + ((size_t)(u >> 4) * M_ROWS + (size_t)((u & 15) >> 1) * N_NODES
               + (m0 + rg * 16 + lm)) * CH
            + (u & 1) * 32 + lq * 8);
    };
    auto LDB = [&](int sk, int t) -> short8 {
        return *(const short8*)(Wp + (size_t)(t * 16 + lm) * KCAT + sk * 32 + lq * 8);
    };

    // x-part: sk=0,1 handled by wave 0 (peeled; keeps main loop branch-free)
    if (w == 0) {
#pragma unroll
        for (int sk = 0; sk < 2; ++sk) {
            short8 a0 = *(const short8*)(Xp + (size_t)(m0 + lm) * CH + sk * 32 + lq * 8);
            short8 a1 = *(const short8*)(Xp + (size_t)(m0 + 16 + lm) * CH + sk * 32 + lq * 8);
#pragma unroll
            for (int t = 0; t < 4; ++t) {
                short8 bf = LDB(sk, t);
                acc[0][t] = __builtin_amdgcn_mfma_f32_16x16x32_bf16(a0, bf, acc[0][t], 0, 0, 0);
                acc[1][t] = __builtin_amdgcn_mfma_f32_16x16x32_bf16(a1, bf, acc[1][t], 0, 0, 0);
            }
        }
    }

    // main: 28 T-ksteps per wave; loads at top of iter, 8 MFMAs at bottom;
    // unroll 2 lets the scheduler hoist next-iter loads over current MFMAs.
    int tb = 2 + w * 28;
#pragma unroll 2
    for (int i = 0; i < 28; ++i) {
        int sk = tb + i;
        short8 a0 = LDA(sk, 0);
        short8 a1 = LDA(sk, 1);
#pragma unroll
        for (int t = 0; t < 4; ++t) {
            short8 bf = LDB(sk, t);
            acc[0][t] = __builtin_amdgcn_mfma_f32_16x16x32_bf16(a0, bf, acc[0][t], 0, 0, 0);
            acc[1][t] = __builtin_amdgcn_mfma_f32_16x16x32_bf16(a1, bf, acc[1][t], 0, 0, 0);
        }
    }

    // cross-wave K-reduction, one pass per row-group (red reused)
#pragma unroll
    for (int rg = 0; rg < 2; ++rg) {
        if (rg) __syncthreads();          // previous reduce done before overwrite
#pragma unroll
        for (int t = 0; t < 4; ++t)
#pragma unroll
            for (int rI = 0; rI < 4; ++rI) red[w][t * 4 + rI][l] = acc[rg][t][rI];
        __syncthreads();
        int col = w * 16 + lm;            // wave w reduces column group t=w
        float b = bias[col];
#pragma unroll
        for (int rI = 0; rI < 4; ++rI) {
            int i2 = w * 4 + rI;
            float sum = red[0][i2][l] + red[1][i2][l] + red[2][i2][l] + red[3][i2][l];
            out[(size_t)(m0 + rg * 16 + lq * 4 + rI) * CH + col] = sum + b;
        }
    }
}

// ---------------- launch ----------------

extern "C" void kernel_launch(void* const* d_in, const int* in_sizes, int n_in,
                              void* d_out, int out_size, void* d_ws, size_t ws_size,
                              hipStream_t stream) {
    (void)in_sizes; (void)n_in; (void)out_size; (void)ws_size;
    const float* x       = (const float*)d_in[0];
    const float* ls_vals = (const float*)d_in[1];
    const float* weight  = (const float*)d_in[2];
    const float* bias    = (const float*)d_in[3];
    const int*   ls_rows = (const int*)d_in[4];
    const int*   ls_cols = (const int*)d_in[5];
    float* out = (float*)d_out;

    char* ws = (char*)d_ws;
    size_t off = 0;
    auto alloc = [&](size_t bytes) -> void* {
        void* p = ws + off;
        off += (bytes + 255) & ~(size_t)255;
        return p;
    };
    int*  chunk_cnt = (int*)alloc((size_t)NCHUNK * NB * sizeof(int));
    int*  btotal    = (int*)alloc(NB * sizeof(int));
    int*  bstart    = (int*)alloc((NB + 1) * sizeof(int));
    int*  row_start = (int*)alloc((M_ROWS + 1) * sizeof(int));
    int2* bedges2   = (int2*)alloc((size_t)E_EDGES * sizeof(int2));
    ushort* Wcat = (ushort*)alloc((size_t)64 * KCAT * sizeof(ushort));
    ushort* xb   = (ushort*)alloc((size_t)N_NODES * CH * sizeof(ushort));
    ushort* Tall = (ushort*)alloc((size_t)7 * M_ROWS * CH * sizeof(ushort));
    // Alias: phase-1 bucket staging lives in Tall seg0 (20.48 MB each; seg0 is
    // first written by spmm#1, which runs after bucket_group has consumed bedges).
    int2* bedges = (int2*)Tall;

    // deterministic bucket build + per-bucket row grouping
    count_kernel<<<NCHUNK, 256, 0, stream>>>(ls_rows, chunk_cnt);
    bscan2_kernel<<<NB, 256, 0, stream>>>(chunk_cnt, btotal);
    bscan_kernel<<<1, 1024, 0, stream>>>(btotal, bstart);
    scatter_kernel<<<NCHUNK, 256, 0, stream>>>(ls_rows, ls_cols, ls_vals, chunk_cnt,
                                               bstart, bedges);
    bucket_group_kernel<<<NB, 256, 0, stream>>>(bstart, bedges, bedges2, row_start);

    // converts
    xconv_kernel<<<(N_NODES * CH) / 256, 256, 0, stream>>>(x, xb);
    wcat_kernel<<<(64 * KCAT) / 256, 256, 0, stream>>>(weight, Wcat);

    ushort* T[8];  // T[k] = seg k-1
    for (int k = 1; k < K_CHEB; ++k) T[k] = Tall + (size_t)(k - 1) * M_ROWS * CH;

    // Chebyshev chain (T1 = L tile(x); Tk = 2 L T_{k-1} - T_{k-2})
    spmm_kernel<1, 0><<<SPMM_BLOCKS, 256, 0, stream>>>(
        row_start, bedges2, xb, xb, T[1], 1.f, 0.f);
    spmm_kernel<0, 2><<<SPMM_BLOCKS, 256, 0, stream>>>(
        row_start, bedges2, T[1], xb, T[2], 2.f, -1.f);
    for (int k = 3; k < K_CHEB; ++k) {
        spmm_kernel<0, 1><<<SPMM_BLOCKS, 256, 0, stream>>>(
            row_start, bedges2, T[k - 1], T[k - 2], T[k], 2.f, -1.f);
    }

    // one concatenated GEMM for all k terms
    gemm_cat_kernel<<<GEMM_BLOCKS, 256, 0, stream>>>(xb, Tall, Wcat, bias, out);
}

// Round 10
// 571.459 us; speedup vs baseline: 1.3060x; 1.3060x over previous
//
#include <hip/hip_runtime.h>
#include <hip/hip_bf16.h>

// Problem constants (from setup_inputs)
#define N_NODES 20000
#define NANG 8
#define CH 64                      // in_size == out_size == 64
#define M_ROWS (NANG * N_NODES)    // 160000
#define E_EDGES (M_ROWS * 16)      // 2560000
#define K_CHEB 8
#define WK_STRIDE (NANG * CH * CH) // 32768 floats per weight[k]
#define BROWS 256                  // rows per bucket (good scatter write-combining)
#define NB (M_ROWS / BROWS)        // 625 buckets
#define NCHUNK 512                 // r6: counting-sort scatter, 5000-edge chunks
#define CHUNK (E_EDGES / NCHUNK)   // 5000
#define SCAN_K (NCHUNK / 256)      // 2 chunks per thread in bscan2
#define SC_RE 20                   // ceil(CHUNK/256) reg-staged edges per thread
#define RPW 4                      // spmm rows per wave (r4 best; r7's 8 and r8's
                                   // scalar-edge variant both regressed -> r6 form)
#define SPMM_BLOCKS (M_ROWS / (4 * RPW))  // 10000 blocks x 4 waves
#define KCAT 3648                  // 64 (x@Wsum) + 7*512 (feat(Tk)@Wk)
#define SK_TOTAL 114               // KCAT/32 ksteps
#define BCAP 5120                  // LDS staging cap (mean 4096, sd 64 -> 16 sigma)
#define GROWS 32                   // gemm rows per block (2 row-groups)
#define GEMM_BLOCKS (N_NODES / GROWS)  // 625

typedef short short8 __attribute__((ext_vector_type(8)));
typedef float f32x4 __attribute__((ext_vector_type(4)));

__device__ __forceinline__ float bf2f(ushort u) {
    return __uint_as_float((unsigned int)u << 16);
}

// ---------------- deterministic bucket build (no global atomics) ----------------

__global__ __launch_bounds__(256) void count_kernel(const int* __restrict__ rows,
                                                    int* __restrict__ chunk_cnt) {
    __shared__ int h[NB];
    int c = blockIdx.x, tid = threadIdx.x;
    for (int i = tid; i < NB; i += 256) h[i] = 0;
    __syncthreads();
    int base = c * CHUNK;
    for (int i = tid; i < CHUNK; i += 256) atomicAdd(&h[rows[base + i] >> 8], 1);
    __syncthreads();
    for (int i = tid; i < NB; i += 256) chunk_cnt[(size_t)c * NB + i] = h[i];
}

// per-bucket scan along the chunk axis. 256 threads x SCAN_K serial chunks each,
// Hillis-Steele over the 256 partials, write back exclusive prefixes.
// chunk_cnt[c][b] -> exclusive prefix over c (bucket-local), btotal[b] = total.
__global__ __launch_bounds__(256) void bscan2_kernel(int* __restrict__ chunk_cnt,
                                                     int* __restrict__ btotal) {
    __shared__ int s[256];
    int b = blockIdx.x, t = threadIdx.x;
    int loc[SCAN_K];
    int sum = 0;
#pragma unroll
    for (int k = 0; k < SCAN_K; ++k) {
        loc[k] = chunk_cnt[(size_t)(t * SCAN_K + k) * NB + b];
        sum += loc[k];
    }
    s[t] = sum;
    __syncthreads();
#pragma unroll
    for (int off = 1; off < 256; off <<= 1) {
        int u = (t >= off) ? s[t - off] : 0;
        __syncthreads();
        s[t] += u;
        __syncthreads();
    }
    int run = s[t] - sum;                 // exclusive prefix of this thread's span
#pragma unroll
    for (int k = 0; k < SCAN_K; ++k) {
        chunk_cnt[(size_t)(t * SCAN_K + k) * NB + b] = run;
        run += loc[k];
    }
    if (t == 255) btotal[b] = s[255];
}

// single-block exclusive scan over NB bucket totals (NB=625 <= 1024)
__global__ void bscan_kernel(const int* __restrict__ btotal, int* __restrict__ bstart) {
    __shared__ int s[1024];
    int t = threadIdx.x;
    int v = (t < NB) ? btotal[t] : 0;
    s[t] = v;
    __syncthreads();
    for (int off = 1; off < 1024; off <<= 1) {
        int u = (t >= off) ? s[t - off] : 0;
        __syncthreads();
        s[t] += u;
        __syncthreads();
    }
    if (t < NB) bstart[t] = s[t] - v;
    if (t == 1023) bstart[NB] = s[1023];
}

// ---------------- scatter v2: LDS counting sort -> SEQUENTIAL global writes -----
// r5 evidence: occupancy 11->43% with duration UNCHANGED (63us) -> scatter was
// bound by the random-8B-write transaction path. Bucket-sort each chunk in LDS,
// write out in sorted order: slot i -> gaddr[bkey[i]] + i, contiguous per run.

__global__ __launch_bounds__(256) void scatter_kernel(
        const int* __restrict__ rows, const int* __restrict__ cols,
        const float* __restrict__ vals, const int* __restrict__ chunk_cnt,
        const int* __restrict__ bstart, int2* __restrict__ bedges) {
    __shared__ int2 stage[CHUNK];      // 40 KB, bucket-sorted edges
    __shared__ ushort bkey[CHUNK];     // 10 KB, bucket id per sorted slot
    __shared__ int hist[NB];
    __shared__ int fill[NB];
    __shared__ int gaddr[NB];          // bstart[b] + chunk_cnt[c][b] - lstart[b]
    __shared__ int sc[256];
    int c = blockIdx.x, tid = threadIdx.x;
    for (int i = tid; i < NB; i += 256) hist[i] = 0;
    __syncthreads();

    // phase A: reg-stage this thread's edges, count buckets
    int base = c * CHUNK;
    int2 eds[SC_RE];
    int keys[SC_RE];
#pragma unroll
    for (int k = 0; k < SC_RE; ++k) {
        int i = tid + k * 256;
        if (i < CHUNK) {
            int e = base + i;
            int r = rows[e];
            eds[k] = make_int2(cols[e] | ((r & 255) << 18), __float_as_int(vals[e]));
            keys[k] = r >> 8;
            atomicAdd(&hist[keys[k]], 1);
        } else keys[k] = -1;
    }
    __syncthreads();

    // phase B: exclusive scan of hist (3 slots/thread, 768 >= NB)
    int loc[3];
    int sum = 0;
    int b0 = tid * 3;
#pragma unroll
    for (int k = 0; k < 3; ++k) {
        int b = b0 + k;
        loc[k] = (b < NB) ? hist[b] : 0;
        sum += loc[k];
    }
    sc[tid] = sum;
    __syncthreads();
#pragma unroll
    for (int off = 1; off < 256; off <<= 1) {
        int u = (tid >= off) ? sc[tid - off] : 0;
        __syncthreads();
        sc[tid] += u;
        __syncthreads();
    }
    int run = sc[tid] - sum;
#pragma unroll
    for (int k = 0; k < 3; ++k) {
        int b = b0 + k;
        if (b < NB) {
            fill[b] = run;
            gaddr[b] = bstart[b] + chunk_cnt[(size_t)c * NB + b] - run;
        }
        run += loc[k];
    }
    __syncthreads();

    // phase C: scatter regs -> bucket-sorted LDS
#pragma unroll
    for (int k = 0; k < SC_RE; ++k) {
        if (keys[k] >= 0) {
            int p = atomicAdd(&fill[keys[k]], 1);
            stage[p] = eds[k];
            bkey[p] = (ushort)keys[k];
        }
    }
    __syncthreads();

    // phase D: sequential write-out (runs contiguous in global too)
    for (int i = tid; i < CHUNK; i += 256) {
        int b = bkey[i];
        bedges[gaddr[b] + i] = stage[i];
    }
}

// per-bucket: group edges by row via LDS staging, then write bout SEQUENTIALLY
// (coalesced; avoids random-8B write amplification). Parallel scan for prefix.
__global__ __launch_bounds__(256) void bucket_group_kernel(
        const int* __restrict__ bstart, const int2* __restrict__ bin,
        int2* __restrict__ bout, int* __restrict__ row_start) {
    __shared__ int cnt[BROWS];
    __shared__ int pref[BROWS];
    __shared__ int fill[BROWS];
    __shared__ int2 ob[BCAP];          // 40 KB staging
    int b = blockIdx.x, tid = threadIdx.x;
    int s = bstart[b], e = bstart[b + 1];
    int n = e - s;
    cnt[tid] = 0;
    __syncthreads();
    int2 eds[20];                      // reg cache (n/256 <= 20 when n <= BCAP)
    int ni = 0;
    for (int i = tid; i < n; i += 256, ++ni) {
        int2 ed = bin[s + i];
        if (ni < 20) eds[ni] = ed;
        atomicAdd(&cnt[(ed.x >> 18) & 255], 1);
    }
    __syncthreads();
    // Hillis-Steele inclusive scan over 256 counters -> exclusive pref
    int v = cnt[tid];
    pref[tid] = v;
    __syncthreads();
#pragma unroll
    for (int off = 1; off < 256; off <<= 1) {
        int u = (tid >= off) ? pref[tid - off] : 0;
        __syncthreads();
        pref[tid] += u;
        __syncthreads();
    }
    int my_excl = pref[tid] - v;
    __syncthreads();
    pref[tid] = my_excl;
    fill[tid] = my_excl;
    __syncthreads();

    if (n <= BCAP) {
        ni = 0;
        for (int i = tid; i < n; i += 256, ++ni) {
            int2 ed = (ni < 20) ? eds[ni] : bin[s + i];
            int p = atomicAdd(&fill[(ed.x >> 18) & 255], 1);
            ob[p] = make_int2(ed.x & 0x3ffff, ed.y);
        }
        __syncthreads();
        for (int i = tid; i < n; i += 256)
            bout[s + i] = ob[i];       // sequential, coalesced
    } else {
        // fallback (statistically unreachable): direct global scatter
        ni = 0;
        for (int i = tid; i < n; i += 256, ++ni) {
            int2 ed = (ni < 20) ? eds[ni] : bin[s + i];
            int p = atomicAdd(&fill[(ed.x >> 18) & 255], 1);
            bout[s + p] = make_int2(ed.x & 0x3ffff, ed.y);
        }
    }
    row_start[b * BROWS + tid] = s + pref[tid];
    if (b == NB - 1 && tid == 0) row_start[M_ROWS] = e;
}

// ---------------- small converts ----------------

__global__ void xconv_kernel(const float* __restrict__ x, ushort* __restrict__ xb) {
    int i = blockIdx.x * 256 + threadIdx.x;
    __hip_bfloat16 v = __float2bfloat16(x[i]);
    xb[i] = *(ushort*)&v;
}

// Wcat[n][kkc], kkc in [0,KCAT): kkc<64 -> sum_a W[0][a*64+kkc][n] (x@Wsum term);
// else k=(kkc-64)/512+1, kk=(kkc-64)%512 -> W[k][kk][n].
__global__ void wcat_kernel(const float* __restrict__ W, ushort* __restrict__ Wcat) {
    int idx = blockIdx.x * 256 + threadIdx.x;    // 64*KCAT = 233472
    int n   = idx / KCAT;
    int kkc = idx - n * KCAT;
    float v;
    if (kkc < 64) {
        v = 0.f;
#pragma unroll
        for (int a = 0; a < NANG; ++a) v += W[(a * 64 + kkc) * 64 + n];
    } else {
        int k  = ((kkc - 64) >> 9) + 1;
        int kk = (kkc - 64) & 511;
        v = W[(size_t)k * WK_STRIDE + kk * 64 + n];
    }
    __hip_bfloat16 b = __float2bfloat16(v);
    Wcat[idx] = *(ushort*)&b;
}

// ---------------- SpMM v3 (r6 form, reverted): 4 rows/wave, readlane edges -------
// r8's scalar-edge variant regressed 62->88us (16 serialized 8B uniform loads
// replaced ONE coalesced 128B vector edge load). The readlane form is best-known.
// r3: VALU 84->43% at constant time; r4: RPW 1->4 = -7us; r7: RPW 8 regressed.
// Model: gather path near L2/L3 delivery limit (328MB/spmm at ~5.3TB/s).

template <int TIN_TILED, int TSUB_MODE>
__global__ __launch_bounds__(256) void spmm_kernel(
        const int* __restrict__ row_start, const int2* __restrict__ edges,
        const ushort* __restrict__ Tin, const ushort* __restrict__ Tsub,
        ushort* __restrict__ Tout, float alpha, float beta) {
    int wid = (blockIdx.x * 256 + threadIdx.x) >> 6;
    int lane = threadIdx.x & 63;
    int r0 = wid * RPW;                // M_ROWS % (4*RPW) == 0 -> always in range
    int l16 = lane & 15;

    // scalar row bounds for RPW rows (uniform addresses -> s_load, issued together)
    int sb[RPW + 1];
#pragma unroll
    for (int j = 0; j <= RPW; ++j)
        sb[j] = __builtin_amdgcn_readfirstlane(row_start[r0 + j]);

    // prefetch first 16-edge block of each row (empty-row-safe clamp; value unused
    // if the row loop body never runs)
    int2 ed[RPW];
#pragma unroll
    for (int j = 0; j < RPW; ++j) {
        int idx = min(sb[j] + l16, sb[j + 1] - 1);
        idx = max(idx, 0);
        ed[j] = edges[idx];
    }

#pragma unroll
    for (int j = 0; j < RPW; ++j) {
        int s = sb[j], e = sb[j + 1];
        float acc0 = 0.f, acc1 = 0.f;
        int2 cur = ed[j];
        for (int base = s; base < e; base += 16) {
            // prefetch next 16-edge block of this row under this block's work
            int2 nxt = cur;
            if (base + 16 < e) {                       // uniform branch
                int idx = min(base + 16 + l16, e - 1);
                nxt = edges[idx];
            }
            // batch the 16 gathers: pure-load loop -> 16 outstanding (1 round-trip)
            ushort raw[16];
#pragma unroll
            for (int i = 0; i < 16; ++i) {
                unsigned c = (unsigned)__builtin_amdgcn_readlane(cur.x, i);
                if (TIN_TILED) c %= N_NODES;           // scalar magic-div
                raw[i] = Tin[(size_t)c * CH + lane];   // saddr + lane offset
            }
#pragma unroll
            for (int i = 0; i < 16; ++i) {
                int wbits = __builtin_amdgcn_readlane(cur.y, i);
                if (base + i >= e) wbits = 0;          // s_cselect (0.0f bits)
                float t = bf2f(raw[i]);
                if (i & 1) acc1 = fmaf(__int_as_float(wbits), t, acc1);
                else       acc0 = fmaf(__int_as_float(wbits), t, acc0);
            }
            cur = nxt;
        }
        int r = r0 + j;
        float v = alpha * (acc0 + acc1);
        size_t oi = (size_t)r * CH + lane;
        if (TSUB_MODE == 1) v += beta * bf2f(Tsub[oi]);
        if (TSUB_MODE == 2) v += beta * bf2f(Tsub[(size_t)((unsigned)r % N_NODES) * CH + lane]);
        __hip_bfloat16 o = __float2bfloat16(v);
        Tout[oi] = *(ushort*)&o;
    }
}

// ---------------- concatenated GEMM: r6 form + depth-4 A-prefetch ring ------------
// r6 counters: FETCH 73.6MB HBM at only 1.2TB/s, all pipes idle -> HBM-latency-
// bound streaming. Little's law: 2 x 16B A-loads in flight per wave is ~20x short
// of what 6TB/s needs. r7 showed more WAVES don't fix it; more LOADS PER WAVE
// might: depth-4 ring pa0/pa1[4] keeps 8 A-loads (128B/wave) in flight across 4
// iterations of MFMA work. Static ring index (i&3 under unroll-4) per rule #20.
// VGPR 52 -> ~84 (still one residency generation, 625 blocks x 4 waves).
// A layout: m=lane&15, k=(lane>>4)*8+j. C/D: col=lane&15, row=(lane>>4)*4+reg [m89].

__global__ __launch_bounds__(256) void gemm_cat_kernel(
        const ushort* __restrict__ xb,    // [N,64]
        const ushort* __restrict__ Tall,  // [7][NANG*N,64]
        const ushort* __restrict__ Wcat,  // [64][KCAT]
        const float* __restrict__ bias,
        float* __restrict__ out) {        // [N,64] fp32
    __shared__ float red[4][16][64];      // 16 KB, conflict-free, reused per rg
    int m0 = blockIdx.x * GROWS;
    int w = threadIdx.x >> 6;             // K-split index 0..3
    int l = threadIdx.x & 63;
    int lm = l & 15;
    int lq = l >> 4;
    const short* Xp = (const short*)xb;
    const short* Tp = (const short*)Tall;
    const short* Wp = (const short*)Wcat;

    f32x4 acc[2][4];
#pragma unroll
    for (int rg = 0; rg < 2; ++rg)
#pragma unroll
        for (int t = 0; t < 4; ++t) acc[rg][t] = (f32x4){0.f, 0.f, 0.f, 0.f};

    // A-fragment load for a T-kstep (sk in [2,114)): seg=(sk-2)>>4, ks=(sk-2)&15,
    // a=ks>>1, half=ks&1.
    auto LDA = [&](int sk, int rg) -> short8 {
        int u = sk - 2;
        return *(const short8*)(Tp
            + ((size_t)(u >> 4) * M_ROWS + (size_t)((u & 15) >> 1) * N_NODES
               + (m0 + rg * 16 + lm)) * CH
            + (u & 1) * 32 + lq * 8);
    };
    auto LDB = [&](int sk, int t) -> short8 {
        return *(const short8*)(Wp + (size_t)(t * 16 + lm) * KCAT + sk * 32 + lq * 8);
    };
    auto MFMA8 = [&](short8 a0, short8 a1, int sk) {
#pragma unroll
        for (int t = 0; t < 4; ++t) {
            short8 bf = LDB(sk, t);
            acc[0][t] = __builtin_amdgcn_mfma_f32_16x16x32_bf16(a0, bf, acc[0][t], 0, 0, 0);
            acc[1][t] = __builtin_amdgcn_mfma_f32_16x16x32_bf16(a1, bf, acc[1][t], 0, 0, 0);
        }
    };

    // x-part: sk=0,1 handled by wave 0 (peeled; keeps main loop branch-free)
    if (w == 0) {
#pragma unroll
        for (int sk = 0; sk < 2; ++sk) {
            short8 a0 = *(const short8*)(Xp + (size_t)(m0 + lm) * CH + sk * 32 + lq * 8);
            short8 a1 = *(const short8*)(Xp + (size_t)(m0 + 16 + lm) * CH + sk * 32 + lq * 8);
            MFMA8(a0, a1, sk);
        }
    }

    // main: 28 T-ksteps per wave, depth-4 software-prefetch ring
    int tb = 2 + w * 28;
    short8 pa0[4], pa1[4];
#pragma unroll
    for (int p = 0; p < 4; ++p) {
        pa0[p] = LDA(tb + p, 0);
        pa1[p] = LDA(tb + p, 1);
    }
#pragma unroll 4
    for (int i = 0; i < 24; ++i) {
        int sk = tb + i;
        short8 a0 = pa0[i & 3];
        short8 a1 = pa1[i & 3];
        pa0[i & 3] = LDA(sk + 4, 0);      // refill slot: 8 A-loads stay in flight
        pa1[i & 3] = LDA(sk + 4, 1);
        MFMA8(a0, a1, sk);
    }
#pragma unroll
    for (int i = 24; i < 28; ++i)
        MFMA8(pa0[i & 3], pa1[i & 3], tb + i);

    // cross-wave K-reduction, one pass per row-group (red reused)
#pragma unroll
    for (int rg = 0; rg < 2; ++rg) {
        if (rg) __syncthreads();          // previous reduce done before overwrite
#pragma unroll
        for (int t = 0; t < 4; ++t)
#pragma unroll
            for (int rI = 0; rI < 4; ++rI) red[w][t * 4 + rI][l] = acc[rg][t][rI];
        __syncthreads();
        int col = w * 16 + lm;            // wave w reduces column group t=w
        float b = bias[col];
#pragma unroll
        for (int rI = 0; rI < 4; ++rI) {
            int i2 = w * 4 + rI;
            float sum = red[0][i2][l] + red[1][i2][l] + red[2][i2][l] + red[3][i2][l];
            out[(size_t)(m0 + rg * 16 + lq * 4 + rI) * CH + col] = sum + b;
        }
    }
}

// ---------------- launch ----------------

extern "C" void kernel_launch(void* const* d_in, const int* in_sizes, int n_in,
                              void* d_out, int out_size, void* d_ws, size_t ws_size,
                              hipStream_t stream) {
    (void)in_sizes; (void)n_in; (void)out_size; (void)ws_size;
    const float* x       = (const float*)d_in[0];
    const float* ls_vals = (const float*)d_in[1];
    const float* weight  = (const float*)d_in[2];
    const float* bias    = (const float*)d_in[3];
    const int*   ls_rows = (const int*)d_in[4];
    const int*   ls_cols = (const int*)d_in[5];
    float* out = (float*)d_out;

    char* ws = (char*)d_ws;
    size_t off = 0;
    auto alloc = [&](size_t bytes) -> void* {
        void* p = ws + off;
        off += (bytes + 255) & ~(size_t)255;
        return p;
    };
    int*  chunk_cnt = (int*)alloc((size_t)NCHUNK * NB * sizeof(int));
    int*  btotal    = (int*)alloc(NB * sizeof(int));
    int*  bstart    = (int*)alloc((NB + 1) * sizeof(int));
    int*  row_start = (int*)alloc((M_ROWS + 1) * sizeof(int));
    int2* bedges2   = (int2*)alloc((size_t)E_EDGES * sizeof(int2));
    ushort* Wcat = (ushort*)alloc((size_t)64 * KCAT * sizeof(ushort));
    ushort* xb   = (ushort*)alloc((size_t)N_NODES * CH * sizeof(ushort));
    ushort* Tall = (ushort*)alloc((size_t)7 * M_ROWS * CH * sizeof(ushort));
    // Alias: phase-1 bucket staging lives in Tall seg0 (20.48 MB each; seg0 is
    // first written by spmm#1, which runs after bucket_group has consumed bedges).
    int2* bedges = (int2*)Tall;

    // deterministic bucket build + per-bucket row grouping
    count_kernel<<<NCHUNK, 256, 0, stream>>>(ls_rows, chunk_cnt);
    bscan2_kernel<<<NB, 256, 0, stream>>>(chunk_cnt, btotal);
    bscan_kernel<<<1, 1024, 0, stream>>>(btotal, bstart);
    scatter_kernel<<<NCHUNK, 256, 0, stream>>>(ls_rows, ls_cols, ls_vals, chunk_cnt,
                                               bstart, bedges);
    bucket_group_kernel<<<NB, 256, 0, stream>>>(bstart, bedges, bedges2, row_start);

    // converts
    xconv_kernel<<<(N_NODES * CH) / 256, 256, 0, stream>>>(x, xb);
    wcat_kernel<<<(64 * KCAT) / 256, 256, 0, stream>>>(weight, Wcat);

    ushort* T[8];  // T[k] = seg k-1
    for (int k = 1; k < K_CHEB; ++k) T[k] = Tall + (size_t)(k - 1) * M_ROWS * CH;

    // Chebyshev chain (T1 = L tile(x); Tk = 2 L T_{k-1} - T_{k-2})
    spmm_kernel<1, 0><<<SPMM_BLOCKS, 256, 0, stream>>>(
        row_start, bedges2, xb, xb, T[1], 1.f, 0.f);
    spmm_kernel<0, 2><<<SPMM_BLOCKS, 256, 0, stream>>>(
        row_start, bedges2, T[1], xb, T[2], 2.f, -1.f);
    for (int k = 3; k < K_CHEB; ++k) {
        spmm_kernel<0, 1><<<SPMM_BLOCKS, 256, 0, stream>>>(
            row_start, bedges2, T[k - 1], T[k - 2], T[k], 2.f, -1.f);
    }

    // one concatenated GEMM for all k terms
    gemm_cat_kernel<<<GEMM_BLOCKS, 256, 0, stream>>>(xb, Tall, Wcat, bias, out);
}